// Round 1
// baseline (222.724 us; speedup 1.0000x reference)
//
#include <hip/hip_runtime.h>
#include <hip/hip_bf16.h>

// Problem constants (from reference setup_inputs)
#define NB 8
#define LQ 512
#define LC 2048
#define DD 768

typedef _Float16 f16x8 __attribute__((ext_vector_type(8)));
typedef _Float16 f16x4 __attribute__((ext_vector_type(4)));
typedef float    f32x4 __attribute__((ext_vector_type(4)));

// ---------------------------------------------------------------------------
// K0: convert Q fp32 -> Qh [b][q][d] fp16  AND  QhT [b][d][q] fp16 (transposed)
// One block handles a 64q x 64d tile. LDS transpose for coalesced stores.
// ---------------------------------------------------------------------------
__global__ __launch_bounds__(256) void preconvert_q(const float* __restrict__ Q,
                                                    _Float16* __restrict__ Qh,
                                                    _Float16* __restrict__ QhT) {
    __shared__ _Float16 lt[64][68];   // +4 pad breaks bank alignment
    const int blk = blockIdx.x;
    const int b   = blk / 96;
    const int rem = blk % 96;
    const int q0  = (rem / 12) * 64;
    const int d0  = (rem % 12) * 64;
    const int t   = threadIdx.x;
    const int tr  = t >> 4;       // 0..15
    const int tc  = t & 15;       // 0..15

    const float* Qb  = Q  + ((size_t)b * LQ + q0) * DD + d0;
    _Float16*    Qhb = Qh + ((size_t)b * LQ + q0) * DD + d0;

#pragma unroll
    for (int i = 0; i < 4; i++) {
        const int row = i * 16 + tr;
        const int col = tc * 4;
        f32x4 v = *(const f32x4*)(Qb + (size_t)row * DD + col);
        f16x4 h;
        h.x = (_Float16)v.x; h.y = (_Float16)v.y;
        h.z = (_Float16)v.z; h.w = (_Float16)v.w;
        *(f16x4*)(Qhb + (size_t)row * DD + col) = h;
        *(f16x4*)&lt[row][col] = h;
    }
    __syncthreads();

    _Float16* QTb = QhT + ((size_t)b * DD + d0) * LQ + q0;
#pragma unroll
    for (int i = 0; i < 4; i++) {
        const int drow = i * 16 + tr;
        const int qc   = tc * 4;
        f16x4 h;
        h.x = lt[qc + 0][drow];
        h.y = lt[qc + 1][drow];
        h.z = lt[qc + 2][drow];
        h.w = lt[qc + 3][drow];
        *(f16x4*)(QTb + (size_t)drow * LQ + qc) = h;
    }
}

// ---------------------------------------------------------------------------
// Main fused kernel. One WG = (batch b, 32 context rows). 256 threads, 4 waves.
// Phase A: S[32,512] = C_tile @ Q^T via 16x16x32 f16 MFMA, NT direct-from-L2.
//   wave w owns q-columns [w*128, w*128+128) -> 2 m-tiles x 8 n-tiles, 64 accs.
// Phase B: softmax over q (shuffle within 16-lane group + LDS across waves),
//   P written to LDS in A-operand-friendly row-major [32][520] fp16 (padded).
// Phase C: awq[32,768] = P @ Q via MFMA; A from LDS, B direct from QhT (L2).
//   wave w owns d-columns [w*192, w*192+192) -> 2 x 12 tiles, 96 accs.
// Epilogue: out = ctx * awq.
// ---------------------------------------------------------------------------
#define PSTRIDE 520   // 512 + 8 halves: 16B-aligned rows, 2-way banks (free)

__global__ __launch_bounds__(256, 2) void gated_attn(const float* __restrict__ ctx,
                                                     const _Float16* __restrict__ Qh,
                                                     const _Float16* __restrict__ QhT,
                                                     float* __restrict__ out) {
    __shared__ _Float16 ldsP[32 * PSTRIDE];
    __shared__ float red_max[4][32];
    __shared__ float red_sum[4][32];

    const int b    = blockIdx.x >> 6;
    const int c0   = (blockIdx.x & 63) * 32;
    const int t    = threadIdx.x;
    const int w    = t >> 6;        // wave id 0..3
    const int lane = t & 63;
    const int quad = lane >> 4;     // 0..3
    const int l15  = lane & 15;     // 0..15

    const float*    Cb  = ctx + ((size_t)b * LC + c0) * DD;
    const _Float16* Qhb = Qh  + (size_t)b * LQ * DD;

    // ---------------- Phase A: S = C_tile @ Q^T ----------------
    f32x4 acc[2][8];
#pragma unroll
    for (int mt = 0; mt < 2; mt++)
#pragma unroll
        for (int nt = 0; nt < 8; nt++)
            acc[mt][nt] = (f32x4){0.f, 0.f, 0.f, 0.f};

    for (int k0 = 0; k0 < DD; k0 += 32) {
        f16x8 afrag[2];
#pragma unroll
        for (int mt = 0; mt < 2; mt++) {
            const float* p = Cb + (size_t)(mt * 16 + l15) * DD + k0 + quad * 8;
            f32x4 f0 = *(const f32x4*)p;
            f32x4 f1 = *(const f32x4*)(p + 4);
            f16x8 h;
            h[0] = (_Float16)f0.x; h[1] = (_Float16)f0.y;
            h[2] = (_Float16)f0.z; h[3] = (_Float16)f0.w;
            h[4] = (_Float16)f1.x; h[5] = (_Float16)f1.y;
            h[6] = (_Float16)f1.z; h[7] = (_Float16)f1.w;
            afrag[mt] = h;
        }
        f16x8 bfrag[8];
#pragma unroll
        for (int nt = 0; nt < 8; nt++)
            bfrag[nt] = *(const f16x8*)(Qhb + (size_t)(w * 128 + nt * 16 + l15) * DD + k0 + quad * 8);
#pragma unroll
        for (int mt = 0; mt < 2; mt++)
#pragma unroll
            for (int nt = 0; nt < 8; nt++)
                acc[mt][nt] = __builtin_amdgcn_mfma_f32_16x16x32_f16(afrag[mt], bfrag[nt], acc[mt][nt], 0, 0, 0);
    }

    // ---------------- Phase B: softmax over q, write P to LDS ----------------
    // lane's rows: mt*16 + quad*4 + r ; lane's cols: w*128 + nt*16 + l15
    float rm[2][4];
#pragma unroll
    for (int mt = 0; mt < 2; mt++)
#pragma unroll
        for (int r = 0; r < 4; r++)
            rm[mt][r] = -1e30f;
#pragma unroll
    for (int mt = 0; mt < 2; mt++)
#pragma unroll
        for (int nt = 0; nt < 8; nt++) {
            rm[mt][0] = fmaxf(rm[mt][0], acc[mt][nt].x);
            rm[mt][1] = fmaxf(rm[mt][1], acc[mt][nt].y);
            rm[mt][2] = fmaxf(rm[mt][2], acc[mt][nt].z);
            rm[mt][3] = fmaxf(rm[mt][3], acc[mt][nt].w);
        }
#pragma unroll
    for (int off = 1; off < 16; off <<= 1)
#pragma unroll
        for (int mt = 0; mt < 2; mt++)
#pragma unroll
            for (int r = 0; r < 4; r++)
                rm[mt][r] = fmaxf(rm[mt][r], __shfl_xor(rm[mt][r], off));
    if (l15 == 0) {
#pragma unroll
        for (int mt = 0; mt < 2; mt++)
#pragma unroll
            for (int r = 0; r < 4; r++)
                red_max[w][mt * 16 + quad * 4 + r] = rm[mt][r];
    }
    __syncthreads();
    float fm[2][4];
#pragma unroll
    for (int mt = 0; mt < 2; mt++)
#pragma unroll
        for (int r = 0; r < 4; r++) {
            const int row = mt * 16 + quad * 4 + r;
            fm[mt][r] = fmaxf(fmaxf(red_max[0][row], red_max[1][row]),
                              fmaxf(red_max[2][row], red_max[3][row]));
        }
    float rs[2][4];
#pragma unroll
    for (int mt = 0; mt < 2; mt++)
#pragma unroll
        for (int r = 0; r < 4; r++)
            rs[mt][r] = 0.f;
#pragma unroll
    for (int mt = 0; mt < 2; mt++)
#pragma unroll
        for (int nt = 0; nt < 8; nt++) {
            float e0 = __expf(acc[mt][nt].x - fm[mt][0]);
            float e1 = __expf(acc[mt][nt].y - fm[mt][1]);
            float e2 = __expf(acc[mt][nt].z - fm[mt][2]);
            float e3 = __expf(acc[mt][nt].w - fm[mt][3]);
            acc[mt][nt].x = e0; acc[mt][nt].y = e1;
            acc[mt][nt].z = e2; acc[mt][nt].w = e3;
            rs[mt][0] += e0; rs[mt][1] += e1; rs[mt][2] += e2; rs[mt][3] += e3;
        }
#pragma unroll
    for (int off = 1; off < 16; off <<= 1)
#pragma unroll
        for (int mt = 0; mt < 2; mt++)
#pragma unroll
            for (int r = 0; r < 4; r++)
                rs[mt][r] += __shfl_xor(rs[mt][r], off);
    if (l15 == 0) {
#pragma unroll
        for (int mt = 0; mt < 2; mt++)
#pragma unroll
            for (int r = 0; r < 4; r++)
                red_sum[w][mt * 16 + quad * 4 + r] = rs[mt][r];
    }
    __syncthreads();
#pragma unroll
    for (int mt = 0; mt < 2; mt++)
#pragma unroll
        for (int r = 0; r < 4; r++) {
            const int row = mt * 16 + quad * 4 + r;
            const float inv = 1.0f / (red_sum[0][row] + red_sum[1][row] +
                                      red_sum[2][row] + red_sum[3][row]);
#pragma unroll
            for (int nt = 0; nt < 8; nt++) {
                const int q = w * 128 + nt * 16 + l15;
                float v = (r == 0 ? acc[mt][nt].x : r == 1 ? acc[mt][nt].y
                          : r == 2 ? acc[mt][nt].z : acc[mt][nt].w);
                ldsP[row * PSTRIDE + q] = (_Float16)(v * inv);
            }
        }
    __syncthreads();

    // ---------------- Phase C: awq = P @ Q, gated epilogue ----------------
    f32x4 acc2[2][12];
#pragma unroll
    for (int mt = 0; mt < 2; mt++)
#pragma unroll
        for (int nt = 0; nt < 12; nt++)
            acc2[mt][nt] = (f32x4){0.f, 0.f, 0.f, 0.f};

    const _Float16* QTb = QhT + (size_t)b * DD * LQ;
    for (int k0 = 0; k0 < LQ; k0 += 32) {
        f16x8 a2[2];
#pragma unroll
        for (int mt = 0; mt < 2; mt++)
            a2[mt] = *(const f16x8*)&ldsP[(mt * 16 + l15) * PSTRIDE + k0 + quad * 8];
        f16x8 bq[12];
#pragma unroll
        for (int nt = 0; nt < 12; nt++)
            bq[nt] = *(const f16x8*)(QTb + (size_t)(w * 192 + nt * 16 + l15) * LQ + k0 + quad * 8);
#pragma unroll
        for (int mt = 0; mt < 2; mt++)
#pragma unroll
            for (int nt = 0; nt < 12; nt++)
                acc2[mt][nt] = __builtin_amdgcn_mfma_f32_16x16x32_f16(a2[mt], bq[nt], acc2[mt][nt], 0, 0, 0);
    }

#pragma unroll
    for (int mt = 0; mt < 2; mt++)
#pragma unroll
        for (int nt = 0; nt < 12; nt++) {
            const int col = w * 192 + nt * 16 + l15;
#pragma unroll
            for (int r = 0; r < 4; r++) {
                const int row = c0 + mt * 16 + quad * 4 + r;
                const size_t idx = ((size_t)b * LC + row) * DD + col;
                float v = (r == 0 ? acc2[mt][nt].x : r == 1 ? acc2[mt][nt].y
                          : r == 2 ? acc2[mt][nt].z : acc2[mt][nt].w);
                out[idx] = ctx[idx] * v;
            }
        }
}

extern "C" void kernel_launch(void* const* d_in, const int* in_sizes, int n_in,
                              void* d_out, int out_size, void* d_ws, size_t ws_size,
                              hipStream_t stream) {
    const float* ctx = (const float*)d_in[0];   // context_emb [8][2048][768] f32
    const float* q   = (const float*)d_in[1];   // query_emb   [8][512][768]  f32
    float* out = (float*)d_out;

    _Float16* Qh  = (_Float16*)d_ws;                       // [8][512][768] fp16
    _Float16* QhT = Qh + (size_t)NB * LQ * DD;             // [8][768][512] fp16

    preconvert_q<<<dim3(NB * 96), dim3(256), 0, stream>>>(q, Qh, QhT);
    gated_attn<<<dim3(NB * (LC / 32)), dim3(256), 0, stream>>>(ctx, Qh, QhT, out);
}

// Round 2
// 220.659 us; speedup vs baseline: 1.0094x; 1.0094x over previous
//
#include <hip/hip_runtime.h>
#include <hip/hip_bf16.h>

// Problem constants (from reference setup_inputs)
#define NB 8
#define LQ 512
#define LC 2048
#define DD 768

typedef _Float16 f16x8 __attribute__((ext_vector_type(8)));
typedef _Float16 f16x4 __attribute__((ext_vector_type(4)));
typedef float    f32x4 __attribute__((ext_vector_type(4)));

// ---------------------------------------------------------------------------
// K0a: elementwise convert ctx fp32 -> Ch fp16 [b][c][d]
// ---------------------------------------------------------------------------
__global__ __launch_bounds__(256) void convert_ctx(const float* __restrict__ src,
                                                   _Float16* __restrict__ dst) {
    const size_t i = (size_t)blockIdx.x * 256 + threadIdx.x;  // 8 elems each
    const f32x4* s = (const f32x4*)src;
    f32x4 a = s[i * 2 + 0];
    f32x4 b = s[i * 2 + 1];
    f16x8 h;
    h[0] = (_Float16)a.x; h[1] = (_Float16)a.y; h[2] = (_Float16)a.z; h[3] = (_Float16)a.w;
    h[4] = (_Float16)b.x; h[5] = (_Float16)b.y; h[6] = (_Float16)b.z; h[7] = (_Float16)b.w;
    ((f16x8*)dst)[i] = h;
}

// ---------------------------------------------------------------------------
// K0b: convert Q fp32 -> Qh [b][q][d] fp16  AND  QhT [b][d][q] fp16
// ---------------------------------------------------------------------------
__global__ __launch_bounds__(256) void preconvert_q(const float* __restrict__ Q,
                                                    _Float16* __restrict__ Qh,
                                                    _Float16* __restrict__ QhT) {
    __shared__ _Float16 lt[64][68];
    const int blk = blockIdx.x;
    const int b   = blk / 96;
    const int rem = blk % 96;
    const int q0  = (rem / 12) * 64;
    const int d0  = (rem % 12) * 64;
    const int t   = threadIdx.x;
    const int tr  = t >> 4;
    const int tc  = t & 15;

    const float* Qb  = Q  + ((size_t)b * LQ + q0) * DD + d0;
    _Float16*    Qhb = Qh + ((size_t)b * LQ + q0) * DD + d0;

#pragma unroll
    for (int i = 0; i < 4; i++) {
        const int row = i * 16 + tr;
        const int col = tc * 4;
        f32x4 v = *(const f32x4*)(Qb + (size_t)row * DD + col);
        f16x4 h;
        h.x = (_Float16)v.x; h.y = (_Float16)v.y;
        h.z = (_Float16)v.z; h.w = (_Float16)v.w;
        *(f16x4*)(Qhb + (size_t)row * DD + col) = h;
        *(f16x4*)&lt[row][col] = h;
    }
    __syncthreads();

    _Float16* QTb = QhT + ((size_t)b * DD + d0) * LQ + q0;
#pragma unroll
    for (int i = 0; i < 4; i++) {
        const int drow = i * 16 + tr;
        const int qc   = tc * 4;
        f16x4 h;
        h.x = lt[qc + 0][drow];
        h.y = lt[qc + 1][drow];
        h.z = lt[qc + 2][drow];
        h.w = lt[qc + 3][drow];
        *(f16x4*)(QTb + (size_t)drow * LQ + qc) = h;
    }
}

// ---------------------------------------------------------------------------
// Main fused kernel v2. One WG = (batch, 32 context rows), 512 threads (8 waves).
//   batch = blockIdx & 7  -> XCD affinity: one batch's Qh/QhT (1.6 MB) per XCD L2.
// Phase A: S[32,512] = Ch_tile @ Qh^T  (fp16 direct loads, no in-loop cvt).
//   wave w owns q-cols [w*64, w*64+64): 2 m-tiles x 4 n-tiles = 8 accs.
// Phase B: softmax over q; P -> LDS [32][520] fp16.
// Phase C: awq[32,768] = P @ Q; wave w owns d-cols [w*96 ..): 2 x 6 tiles.
// Epilogue: out = gate * awq  (gate from Ch if available, else ctx fp32).
// ---------------------------------------------------------------------------
#define PSTRIDE 520   // 512+8 halves: 16B-aligned rows, 2-way banks (free)

template <bool USE_CH>
__global__ __launch_bounds__(512, 4) void gated_attn(const float* __restrict__ ctx,
                                                     const _Float16* __restrict__ Ch,
                                                     const _Float16* __restrict__ Qh,
                                                     const _Float16* __restrict__ QhT,
                                                     float* __restrict__ out) {
    __shared__ _Float16 ldsP[32 * PSTRIDE];
    __shared__ float red_max[8][32];
    __shared__ float red_sum[8][32];

    const int b    = blockIdx.x & 7;          // XCD-affine batch
    const int c0   = (blockIdx.x >> 3) * 32;  // context tile
    const int t    = threadIdx.x;
    const int w    = t >> 6;                  // wave 0..7
    const int lane = t & 63;
    const int quad = lane >> 4;
    const int l15  = lane & 15;

    const float*    Cb  = ctx + ((size_t)b * LC + c0) * DD;
    const _Float16* Chb = USE_CH ? (Ch + ((size_t)b * LC + c0) * DD) : nullptr;
    const _Float16* Qhb = Qh  + (size_t)b * LQ * DD;

    // ---------------- Phase A ----------------
    f32x4 acc[2][4];
#pragma unroll
    for (int mt = 0; mt < 2; mt++)
#pragma unroll
        for (int nt = 0; nt < 4; nt++)
            acc[mt][nt] = (f32x4){0.f, 0.f, 0.f, 0.f};

    for (int k0 = 0; k0 < DD; k0 += 32) {
        f16x8 afrag[2];
#pragma unroll
        for (int mt = 0; mt < 2; mt++) {
            if (USE_CH) {
                afrag[mt] = *(const f16x8*)(Chb + (size_t)(mt * 16 + l15) * DD + k0 + quad * 8);
            } else {
                const float* p = Cb + (size_t)(mt * 16 + l15) * DD + k0 + quad * 8;
                f32x4 f0 = *(const f32x4*)p;
                f32x4 f1 = *(const f32x4*)(p + 4);
                f16x8 h;
                h[0] = (_Float16)f0.x; h[1] = (_Float16)f0.y;
                h[2] = (_Float16)f0.z; h[3] = (_Float16)f0.w;
                h[4] = (_Float16)f1.x; h[5] = (_Float16)f1.y;
                h[6] = (_Float16)f1.z; h[7] = (_Float16)f1.w;
                afrag[mt] = h;
            }
        }
        f16x8 bfrag[4];
#pragma unroll
        for (int nt = 0; nt < 4; nt++)
            bfrag[nt] = *(const f16x8*)(Qhb + (size_t)(w * 64 + nt * 16 + l15) * DD + k0 + quad * 8);
#pragma unroll
        for (int mt = 0; mt < 2; mt++)
#pragma unroll
            for (int nt = 0; nt < 4; nt++)
                acc[mt][nt] = __builtin_amdgcn_mfma_f32_16x16x32_f16(afrag[mt], bfrag[nt], acc[mt][nt], 0, 0, 0);
    }

    // ---------------- Phase B: softmax over q ----------------
    float rm[2][4];
#pragma unroll
    for (int mt = 0; mt < 2; mt++)
#pragma unroll
        for (int r = 0; r < 4; r++)
            rm[mt][r] = -1e30f;
#pragma unroll
    for (int mt = 0; mt < 2; mt++)
#pragma unroll
        for (int nt = 0; nt < 4; nt++) {
            rm[mt][0] = fmaxf(rm[mt][0], acc[mt][nt].x);
            rm[mt][1] = fmaxf(rm[mt][1], acc[mt][nt].y);
            rm[mt][2] = fmaxf(rm[mt][2], acc[mt][nt].z);
            rm[mt][3] = fmaxf(rm[mt][3], acc[mt][nt].w);
        }
#pragma unroll
    for (int off = 1; off < 16; off <<= 1)
#pragma unroll
        for (int mt = 0; mt < 2; mt++)
#pragma unroll
            for (int r = 0; r < 4; r++)
                rm[mt][r] = fmaxf(rm[mt][r], __shfl_xor(rm[mt][r], off));
    if (l15 == 0) {
#pragma unroll
        for (int mt = 0; mt < 2; mt++)
#pragma unroll
            for (int r = 0; r < 4; r++)
                red_max[w][mt * 16 + quad * 4 + r] = rm[mt][r];
    }
    __syncthreads();
    float fm[2][4];
#pragma unroll
    for (int mt = 0; mt < 2; mt++)
#pragma unroll
        for (int r = 0; r < 4; r++) {
            const int row = mt * 16 + quad * 4 + r;
            float m0 = fmaxf(fmaxf(red_max[0][row], red_max[1][row]),
                             fmaxf(red_max[2][row], red_max[3][row]));
            float m1 = fmaxf(fmaxf(red_max[4][row], red_max[5][row]),
                             fmaxf(red_max[6][row], red_max[7][row]));
            fm[mt][r] = fmaxf(m0, m1);
        }
    float rs[2][4];
#pragma unroll
    for (int mt = 0; mt < 2; mt++)
#pragma unroll
        for (int r = 0; r < 4; r++)
            rs[mt][r] = 0.f;
#pragma unroll
    for (int mt = 0; mt < 2; mt++)
#pragma unroll
        for (int nt = 0; nt < 4; nt++) {
            float e0 = __expf(acc[mt][nt].x - fm[mt][0]);
            float e1 = __expf(acc[mt][nt].y - fm[mt][1]);
            float e2 = __expf(acc[mt][nt].z - fm[mt][2]);
            float e3 = __expf(acc[mt][nt].w - fm[mt][3]);
            acc[mt][nt].x = e0; acc[mt][nt].y = e1;
            acc[mt][nt].z = e2; acc[mt][nt].w = e3;
            rs[mt][0] += e0; rs[mt][1] += e1; rs[mt][2] += e2; rs[mt][3] += e3;
        }
#pragma unroll
    for (int off = 1; off < 16; off <<= 1)
#pragma unroll
        for (int mt = 0; mt < 2; mt++)
#pragma unroll
            for (int r = 0; r < 4; r++)
                rs[mt][r] += __shfl_xor(rs[mt][r], off);
    if (l15 == 0) {
#pragma unroll
        for (int mt = 0; mt < 2; mt++)
#pragma unroll
            for (int r = 0; r < 4; r++)
                red_sum[w][mt * 16 + quad * 4 + r] = rs[mt][r];
    }
    __syncthreads();
#pragma unroll
    for (int mt = 0; mt < 2; mt++)
#pragma unroll
        for (int r = 0; r < 4; r++) {
            const int row = mt * 16 + quad * 4 + r;
            float s = 0.f;
#pragma unroll
            for (int j = 0; j < 8; j++) s += red_sum[j][row];
            const float inv = 1.0f / s;
#pragma unroll
            for (int nt = 0; nt < 4; nt++) {
                const int q = w * 64 + nt * 16 + l15;
                float v = (r == 0 ? acc[mt][nt].x : r == 1 ? acc[mt][nt].y
                          : r == 2 ? acc[mt][nt].z : acc[mt][nt].w);
                ldsP[row * PSTRIDE + q] = (_Float16)(v * inv);
            }
        }
    __syncthreads();

    // ---------------- Phase C: awq = P @ Q ----------------
    f32x4 acc2[2][6];
#pragma unroll
    for (int mt = 0; mt < 2; mt++)
#pragma unroll
        for (int nt = 0; nt < 6; nt++)
            acc2[mt][nt] = (f32x4){0.f, 0.f, 0.f, 0.f};

    const _Float16* QTb = QhT + (size_t)b * DD * LQ;
    for (int k0 = 0; k0 < LQ; k0 += 32) {
        f16x8 a2[2];
#pragma unroll
        for (int mt = 0; mt < 2; mt++)
            a2[mt] = *(const f16x8*)&ldsP[(mt * 16 + l15) * PSTRIDE + k0 + quad * 8];
        f16x8 bq[6];
#pragma unroll
        for (int nt = 0; nt < 6; nt++)
            bq[nt] = *(const f16x8*)(QTb + (size_t)(w * 96 + nt * 16 + l15) * LQ + k0 + quad * 8);
#pragma unroll
        for (int mt = 0; mt < 2; mt++)
#pragma unroll
            for (int nt = 0; nt < 6; nt++)
                acc2[mt][nt] = __builtin_amdgcn_mfma_f32_16x16x32_f16(a2[mt], bq[nt], acc2[mt][nt], 0, 0, 0);
    }

    // ---------------- Epilogue: out = gate * awq ----------------
#pragma unroll
    for (int mt = 0; mt < 2; mt++)
#pragma unroll
        for (int nt = 0; nt < 6; nt++) {
            const int col = w * 96 + nt * 16 + l15;
#pragma unroll
            for (int r = 0; r < 4; r++) {
                const int rl  = mt * 16 + quad * 4 + r;
                const int row = c0 + rl;
                const size_t idx = ((size_t)b * LC + row) * DD + col;
                float v = (r == 0 ? acc2[mt][nt].x : r == 1 ? acc2[mt][nt].y
                          : r == 2 ? acc2[mt][nt].z : acc2[mt][nt].w);
                float g = USE_CH ? (float)Chb[(size_t)rl * DD + col] : ctx[idx];
                out[idx] = g * v;
            }
        }
}

extern "C" void kernel_launch(void* const* d_in, const int* in_sizes, int n_in,
                              void* d_out, int out_size, void* d_ws, size_t ws_size,
                              hipStream_t stream) {
    const float* ctx = (const float*)d_in[0];   // [8][2048][768] f32
    const float* q   = (const float*)d_in[1];   // [8][512][768]  f32
    float* out = (float*)d_out;

    const size_t nQ = (size_t)NB * LQ * DD;     // 3,145,728
    const size_t nC = (size_t)NB * LC * DD;     // 12,582,912
    _Float16* Qh  = (_Float16*)d_ws;
    _Float16* QhT = Qh + nQ;
    _Float16* Ch  = QhT + nQ;
    const bool use_ch = ws_size >= (2 * nQ + nC) * sizeof(_Float16);

    preconvert_q<<<dim3(NB * 96), dim3(256), 0, stream>>>(q, Qh, QhT);
    if (use_ch) {
        convert_ctx<<<dim3((int)(nC / (256 * 8))), dim3(256), 0, stream>>>(ctx, Ch);
        gated_attn<true><<<dim3(NB * (LC / 32)), dim3(512), 0, stream>>>(ctx, Ch, Qh, QhT, out);
    } else {
        gated_attn<false><<<dim3(NB * (LC / 32)), dim3(512), 0, stream>>>(ctx, nullptr, Qh, QhT, out);
    }
}

// Round 3
// 201.645 us; speedup vs baseline: 1.1045x; 1.0943x over previous
//
#include <hip/hip_runtime.h>
#include <hip/hip_bf16.h>

// Problem constants (from reference setup_inputs)
#define NB 8
#define LQ 512
#define LC 2048
#define DD 768

typedef _Float16 f16x8 __attribute__((ext_vector_type(8)));
typedef _Float16 f16x4 __attribute__((ext_vector_type(4)));
typedef float    f32x4 __attribute__((ext_vector_type(4)));

// ---------------------------------------------------------------------------
// K0a: elementwise convert ctx fp32 -> Ch fp16 [b][c][d]
// ---------------------------------------------------------------------------
__global__ __launch_bounds__(256) void convert_ctx(const float* __restrict__ src,
                                                   _Float16* __restrict__ dst) {
    const size_t i = (size_t)blockIdx.x * 256 + threadIdx.x;  // 8 elems each
    const f32x4* s = (const f32x4*)src;
    f32x4 a = s[i * 2 + 0];
    f32x4 b = s[i * 2 + 1];
    f16x8 h;
    h[0] = (_Float16)a.x; h[1] = (_Float16)a.y; h[2] = (_Float16)a.z; h[3] = (_Float16)a.w;
    h[4] = (_Float16)b.x; h[5] = (_Float16)b.y; h[6] = (_Float16)b.z; h[7] = (_Float16)b.w;
    ((f16x8*)dst)[i] = h;
}

// ---------------------------------------------------------------------------
// K0b: convert Q fp32 -> Qh [b][q][d] fp16  AND  QhT [b][d][q] fp16
// ---------------------------------------------------------------------------
__global__ __launch_bounds__(256) void preconvert_q(const float* __restrict__ Q,
                                                    _Float16* __restrict__ Qh,
                                                    _Float16* __restrict__ QhT) {
    __shared__ _Float16 lt[64][68];
    const int blk = blockIdx.x;
    const int b   = blk / 96;
    const int rem = blk % 96;
    const int q0  = (rem / 12) * 64;
    const int d0  = (rem % 12) * 64;
    const int t   = threadIdx.x;
    const int tr  = t >> 4;
    const int tc  = t & 15;

    const float* Qb  = Q  + ((size_t)b * LQ + q0) * DD + d0;
    _Float16*    Qhb = Qh + ((size_t)b * LQ + q0) * DD + d0;

#pragma unroll
    for (int i = 0; i < 4; i++) {
        const int row = i * 16 + tr;
        const int col = tc * 4;
        f32x4 v = *(const f32x4*)(Qb + (size_t)row * DD + col);
        f16x4 h;
        h.x = (_Float16)v.x; h.y = (_Float16)v.y;
        h.z = (_Float16)v.z; h.w = (_Float16)v.w;
        *(f16x4*)(Qhb + (size_t)row * DD + col) = h;
        *(f16x4*)&lt[row][col] = h;
    }
    __syncthreads();

    _Float16* QTb = QhT + ((size_t)b * DD + d0) * LQ + q0;
#pragma unroll
    for (int i = 0; i < 4; i++) {
        const int drow = i * 16 + tr;
        const int qc   = tc * 4;
        f16x4 h;
        h.x = lt[qc + 0][drow];
        h.y = lt[qc + 1][drow];
        h.z = lt[qc + 2][drow];
        h.w = lt[qc + 3][drow];
        *(f16x4*)(QTb + (size_t)drow * LQ + qc) = h;
    }
}

// ---------------------------------------------------------------------------
// Main fused kernel v3. One WG = (batch, 32 ctx rows), 512 threads (8 waves).
// Phase A: stage Ch tile (32x768 fp16) in LDS once (stride 776 -> 2-way banks,
//   free). K-loop: ds_read A frags + depth-3 register-rotated B (Qh) prefetch,
//   no barriers in loop.  S[32,512], wave w owns q-cols [w*64, w*64+64).
// Phase B: softmax over q; P -> LDS [32][520] fp16 (aliases ldsA).
// Phase C: awq = P @ Q; A from ldsP, B (QhT) depth-2 register prefetch.
// Epilogue: out = Ch * awq (Ch re-read is an L2 hit).
// ---------------------------------------------------------------------------
#define LDSA_STRIDE 776   // 768+8 halves: 16B-aligned rows, 2-way banks (free)
#define PSTRIDE     520   // 512+8 halves: 16B-aligned rows, 2-way banks (free)
#define LDSA_BYTES  (32 * LDSA_STRIDE * 2)   // 49664

template <bool USE_CH>
__global__ __launch_bounds__(512, 4) void gated_attn(const float* __restrict__ ctx,
                                                     const _Float16* __restrict__ Ch,
                                                     const _Float16* __restrict__ Qh,
                                                     const _Float16* __restrict__ QhT,
                                                     float* __restrict__ out) {
    __shared__ __align__(16) char smem[LDSA_BYTES + 2 * 8 * 32 * 4];
    _Float16* ldsA = (_Float16*)smem;                  // phase A: staged Ch tile
    _Float16* ldsP = (_Float16*)smem;                  // phase B/C: P (aliases ldsA)
    float (*red_max)[32] = (float (*)[32])(smem + LDSA_BYTES);
    float (*red_sum)[32] = red_max + 8;

    const int b    = blockIdx.x & 7;          // XCD-affine batch
    const int c0   = (blockIdx.x >> 3) * 32;  // context tile
    const int t    = threadIdx.x;
    const int w    = t >> 6;                  // wave 0..7
    const int lane = t & 63;
    const int quad = lane >> 4;
    const int l15  = lane & 15;

    const float*    Cb  = ctx + ((size_t)b * LC + c0) * DD;
    const _Float16* Chb = USE_CH ? (Ch + ((size_t)b * LC + c0) * DD) : nullptr;
    const _Float16* Qhb = Qh + (size_t)b * LQ * DD;

    // ---------------- Stage A-tile into LDS (32 rows x 768 halves) ----------
    // 3072 chunks of 16B; 6 chunks per thread, global-coalesced.
#pragma unroll
    for (int i = 0; i < 6; i++) {
        const int idx  = i * 512 + t;
        const int row  = idx / 96;
        const int colc = idx % 96;        // 8-half chunk index
        f16x8 v;
        if (USE_CH) {
            v = *(const f16x8*)(Chb + (size_t)row * DD + colc * 8);
        } else {
            const float* p = Cb + (size_t)row * DD + colc * 8;
            f32x4 f0 = *(const f32x4*)p;
            f32x4 f1 = *(const f32x4*)(p + 4);
            v[0] = (_Float16)f0.x; v[1] = (_Float16)f0.y;
            v[2] = (_Float16)f0.z; v[3] = (_Float16)f0.w;
            v[4] = (_Float16)f1.x; v[5] = (_Float16)f1.y;
            v[6] = (_Float16)f1.z; v[7] = (_Float16)f1.w;
        }
        *(f16x8*)&ldsA[row * LDSA_STRIDE + colc * 8] = v;
    }
    __syncthreads();

    // ---------------- Phase A: S = A_tile @ Qh^T ----------------
    f32x4 acc[2][4];
#pragma unroll
    for (int mt = 0; mt < 2; mt++)
#pragma unroll
        for (int nt = 0; nt < 4; nt++)
            acc[mt][nt] = (f32x4){0.f, 0.f, 0.f, 0.f};

    // depth-3 rotating register buffers for B (Qh) fragments
    f16x8 bb[3][4];
#pragma unroll
    for (int p = 0; p < 3; p++)
#pragma unroll
        for (int nt = 0; nt < 4; nt++)
            bb[p][nt] = *(const f16x8*)(Qhb + (size_t)(w * 64 + nt * 16 + l15) * DD + p * 32 + quad * 8);

#pragma unroll
    for (int kc = 0; kc < 24; kc++) {
        const int k0 = kc * 32;
        f16x8 a0 = *(const f16x8*)&ldsA[(size_t)l15        * LDSA_STRIDE + k0 + quad * 8];
        f16x8 a1 = *(const f16x8*)&ldsA[(size_t)(16 + l15) * LDSA_STRIDE + k0 + quad * 8];
#pragma unroll
        for (int nt = 0; nt < 4; nt++) {
            acc[0][nt] = __builtin_amdgcn_mfma_f32_16x16x32_f16(a0, bb[kc % 3][nt], acc[0][nt], 0, 0, 0);
            acc[1][nt] = __builtin_amdgcn_mfma_f32_16x16x32_f16(a1, bb[kc % 3][nt], acc[1][nt], 0, 0, 0);
        }
        if (kc + 3 < 24) {
#pragma unroll
            for (int nt = 0; nt < 4; nt++)
                bb[kc % 3][nt] = *(const f16x8*)(Qhb + (size_t)(w * 64 + nt * 16 + l15) * DD + (k0 + 96) + quad * 8);
        }
    }

    // ---------------- Phase B: softmax over q ----------------
    float rm[2][4];
#pragma unroll
    for (int mt = 0; mt < 2; mt++)
#pragma unroll
        for (int r = 0; r < 4; r++)
            rm[mt][r] = -1e30f;
#pragma unroll
    for (int mt = 0; mt < 2; mt++)
#pragma unroll
        for (int nt = 0; nt < 4; nt++) {
            rm[mt][0] = fmaxf(rm[mt][0], acc[mt][nt].x);
            rm[mt][1] = fmaxf(rm[mt][1], acc[mt][nt].y);
            rm[mt][2] = fmaxf(rm[mt][2], acc[mt][nt].z);
            rm[mt][3] = fmaxf(rm[mt][3], acc[mt][nt].w);
        }
#pragma unroll
    for (int off = 1; off < 16; off <<= 1)
#pragma unroll
        for (int mt = 0; mt < 2; mt++)
#pragma unroll
            for (int r = 0; r < 4; r++)
                rm[mt][r] = fmaxf(rm[mt][r], __shfl_xor(rm[mt][r], off));
    if (l15 == 0) {
#pragma unroll
        for (int mt = 0; mt < 2; mt++)
#pragma unroll
            for (int r = 0; r < 4; r++)
                red_max[w][mt * 16 + quad * 4 + r] = rm[mt][r];
    }
    __syncthreads();
    float fm[2][4];
#pragma unroll
    for (int mt = 0; mt < 2; mt++)
#pragma unroll
        for (int r = 0; r < 4; r++) {
            const int row = mt * 16 + quad * 4 + r;
            float m0 = fmaxf(fmaxf(red_max[0][row], red_max[1][row]),
                             fmaxf(red_max[2][row], red_max[3][row]));
            float m1 = fmaxf(fmaxf(red_max[4][row], red_max[5][row]),
                             fmaxf(red_max[6][row], red_max[7][row]));
            fm[mt][r] = fmaxf(m0, m1);
        }
    float rs[2][4];
#pragma unroll
    for (int mt = 0; mt < 2; mt++)
#pragma unroll
        for (int r = 0; r < 4; r++)
            rs[mt][r] = 0.f;
#pragma unroll
    for (int mt = 0; mt < 2; mt++)
#pragma unroll
        for (int nt = 0; nt < 4; nt++) {
            float e0 = __expf(acc[mt][nt].x - fm[mt][0]);
            float e1 = __expf(acc[mt][nt].y - fm[mt][1]);
            float e2 = __expf(acc[mt][nt].z - fm[mt][2]);
            float e3 = __expf(acc[mt][nt].w - fm[mt][3]);
            acc[mt][nt].x = e0; acc[mt][nt].y = e1;
            acc[mt][nt].z = e2; acc[mt][nt].w = e3;
            rs[mt][0] += e0; rs[mt][1] += e1; rs[mt][2] += e2; rs[mt][3] += e3;
        }
#pragma unroll
    for (int off = 1; off < 16; off <<= 1)
#pragma unroll
        for (int mt = 0; mt < 2; mt++)
#pragma unroll
            for (int r = 0; r < 4; r++)
                rs[mt][r] += __shfl_xor(rs[mt][r], off);
    if (l15 == 0) {
#pragma unroll
        for (int mt = 0; mt < 2; mt++)
#pragma unroll
            for (int r = 0; r < 4; r++)
                red_sum[w][mt * 16 + quad * 4 + r] = rs[mt][r];
    }
    __syncthreads();
#pragma unroll
    for (int mt = 0; mt < 2; mt++)
#pragma unroll
        for (int r = 0; r < 4; r++) {
            const int row = mt * 16 + quad * 4 + r;
            float s = 0.f;
#pragma unroll
            for (int j = 0; j < 8; j++) s += red_sum[j][row];
            const float inv = 1.0f / s;
#pragma unroll
            for (int nt = 0; nt < 4; nt++) {
                const int q = w * 64 + nt * 16 + l15;
                float v = (r == 0 ? acc[mt][nt].x : r == 1 ? acc[mt][nt].y
                          : r == 2 ? acc[mt][nt].z : acc[mt][nt].w);
                ldsP[row * PSTRIDE + q] = (_Float16)(v * inv);
            }
        }
    __syncthreads();

    // ---------------- Phase C: awq = P @ Q ----------------
    f32x4 acc2[2][6];
#pragma unroll
    for (int mt = 0; mt < 2; mt++)
#pragma unroll
        for (int nt = 0; nt < 6; nt++)
            acc2[mt][nt] = (f32x4){0.f, 0.f, 0.f, 0.f};

    const _Float16* QTb = QhT + (size_t)b * DD * LQ;
    // depth-2 rotating buffers for B (QhT) fragments
    f16x8 cb[2][6];
#pragma unroll
    for (int p = 0; p < 2; p++)
#pragma unroll
        for (int nt = 0; nt < 6; nt++)
            cb[p][nt] = *(const f16x8*)(QTb + (size_t)(w * 96 + nt * 16 + l15) * LQ + p * 32 + quad * 8);

#pragma unroll
    for (int kc = 0; kc < 16; kc++) {
        const int k0 = kc * 32;
        f16x8 a0 = *(const f16x8*)&ldsP[(size_t)l15        * PSTRIDE + k0 + quad * 8];
        f16x8 a1 = *(const f16x8*)&ldsP[(size_t)(16 + l15) * PSTRIDE + k0 + quad * 8];
#pragma unroll
        for (int nt = 0; nt < 6; nt++) {
            acc2[0][nt] = __builtin_amdgcn_mfma_f32_16x16x32_f16(a0, cb[kc & 1][nt], acc2[0][nt], 0, 0, 0);
            acc2[1][nt] = __builtin_amdgcn_mfma_f32_16x16x32_f16(a1, cb[kc & 1][nt], acc2[1][nt], 0, 0, 0);
        }
        if (kc + 2 < 16) {
#pragma unroll
            for (int nt = 0; nt < 6; nt++)
                cb[kc & 1][nt] = *(const f16x8*)(QTb + (size_t)(w * 96 + nt * 16 + l15) * LQ + (k0 + 64) + quad * 8);
        }
    }

    // ---------------- Epilogue: out = gate * awq ----------------
#pragma unroll
    for (int mt = 0; mt < 2; mt++)
#pragma unroll
        for (int nt = 0; nt < 6; nt++) {
            const int col = w * 96 + nt * 16 + l15;
#pragma unroll
            for (int r = 0; r < 4; r++) {
                const int rl  = mt * 16 + quad * 4 + r;
                const int row = c0 + rl;
                const size_t idx = ((size_t)b * LC + row) * DD + col;
                float v = (r == 0 ? acc2[mt][nt].x : r == 1 ? acc2[mt][nt].y
                          : r == 2 ? acc2[mt][nt].z : acc2[mt][nt].w);
                float g = USE_CH ? (float)Chb[(size_t)rl * DD + col] : ctx[idx];
                out[idx] = g * v;
            }
        }
}

extern "C" void kernel_launch(void* const* d_in, const int* in_sizes, int n_in,
                              void* d_out, int out_size, void* d_ws, size_t ws_size,
                              hipStream_t stream) {
    const float* ctx = (const float*)d_in[0];   // [8][2048][768] f32
    const float* q   = (const float*)d_in[1];   // [8][512][768]  f32
    float* out = (float*)d_out;

    const size_t nQ = (size_t)NB * LQ * DD;     // 3,145,728
    const size_t nC = (size_t)NB * LC * DD;     // 12,582,912
    _Float16* Qh  = (_Float16*)d_ws;
    _Float16* QhT = Qh + nQ;
    _Float16* Ch  = QhT + nQ;
    const bool use_ch = ws_size >= (2 * nQ + nC) * sizeof(_Float16);

    preconvert_q<<<dim3(NB * 96), dim3(256), 0, stream>>>(q, Qh, QhT);
    if (use_ch) {
        convert_ctx<<<dim3((int)(nC / (256 * 8))), dim3(256), 0, stream>>>(ctx, Ch);
        gated_attn<true><<<dim3(NB * (LC / 32)), dim3(512), 0, stream>>>(ctx, Ch, Qh, QhT, out);
    } else {
        gated_attn<false><<<dim3(NB * (LC / 32)), dim3(512), 0, stream>>>(ctx, nullptr, Qh, QhT, out);
    }
}